// Round 19
// baseline (848.337 us; speedup 1.0000x reference)
//
#include <hip/hip_runtime.h>
#include <hip/hip_bf16.h>

// LinearFLH: out[m,n] = sx[m]*sw[n]*(x[m,:].w[n,:]) + bias[n]
// M=8192, N=11008, K=4096. All harness buffers FLOAT32 (fp16 ref -> "else
// float" rule). Pipeline: (1) f32->bf16 convert of X,W into d_ws, (2) GEMM.
// R19: OCCUPANCY AXIS (schedule axis exhausted: 10 variants all 699-793us,
// MfmaUtil 42-49%, 2 waves/SIMD lockstep). 128x128 tile, 256 thr (4 waves),
// 64x64 slab/wave -> acc 64 regs; single-buffer 32 KiB LDS; launch_bounds
// (256,3) -> 3 waves/SIMD, ~3 blocks/CU. Independent blocks overlap each
// other's DMA-drain/barrier with MFMA (TLP replaces the failed ILP).
// Sync = R10-proven: reads ; barrier(drains lgkm) ; stage kt+1 ; MFMA ;
// next-iter barrier drains vmcnt -> tile ready. Deterministic.

#define M_DIM 8192
#define N_DIM 11008
#define K_DIM 4096
#define BM 128
#define BN 128
#define BK 64
#define NT (K_DIM / BK)                       // 64 K-tiles
#define NWG ((M_DIM / BM) * (N_DIM / BN))     // 64*86 = 5504 = 8*688

#define X_ELEMS (M_DIM * K_DIM)
#define W_ELEMS (N_DIM * K_DIM)
#define WS_NEEDED ((size_t)(X_ELEMS + W_ELEMS) * 2)

typedef __bf16 bf16x8 __attribute__((ext_vector_type(8)));
typedef float f32x4 __attribute__((ext_vector_type(4)));
typedef unsigned short u16x4 __attribute__((ext_vector_type(4)));
typedef unsigned short u16x8 __attribute__((ext_vector_type(8)));

typedef __attribute__((address_space(3))) void lds_void;
typedef const __attribute__((address_space(1))) void gmem_void;

// f32 -> bf16 bits, round-to-nearest-even (inputs finite)
__device__ __forceinline__ unsigned short f2bf(float f) {
    union { float f; unsigned int u; } c; c.f = f;
    unsigned int r = c.u + 0x7FFFu + ((c.u >> 16) & 1u);
    return (unsigned short)(r >> 16);
}

// ---------------- elementwise convert: f32 -> bf16 (proven R8) ----------------
__global__ __launch_bounds__(256) void convert_f32_to_bf16(
    const float* __restrict__ in, unsigned short* __restrict__ out, int n)
{
    int idx = (blockIdx.x * 256 + threadIdx.x) * 8;
    const int stride = gridDim.x * 256 * 8;
    for (; idx < n; idx += stride) {
        const f32x4 a = *(const f32x4*)(in + idx);
        const f32x4 b = *(const f32x4*)(in + idx + 4);
        u16x8 o;
        #pragma unroll
        for (int q = 0; q < 4; ++q) { o[q] = f2bf(a[q]); o[q + 4] = f2bf(b[q]); }
        *(u16x8*)(out + idx) = o;
    }
}

// ---------------- main GEMM: 128x128, 4 waves, single-buf, ~3 blocks/CU ----------------
// LDS (ushort): A [128][64] @0, B [128][64] @8192. 32 KiB total.
// T2 swizzle (both sides, rule #21): lds[row][col] = global[row][col ^ ((row&7)<<3)].
__global__ __launch_bounds__(256, 3) void linear_flh_gemm_128occ(
    const unsigned short* __restrict__ Xb,   // [M,K] bf16 bits (ws)
    const unsigned short* __restrict__ Wb,   // [N,K] bf16 bits (ws)
    const float* __restrict__ SX,            // [M]
    const float* __restrict__ SW,            // [N]
    const float* __restrict__ BIAS,          // [N]
    float* __restrict__ OUT)                 // [M,N] f32
{
    __shared__ unsigned short lds[16384];    // 32 KiB

    const int t    = threadIdx.x;     // 0..255
    const int lane = t & 63;
    const int wid  = t >> 6;          // 0..3
    const int wr   = wid >> 1;        // wave row 0..1 (64-row slab)
    const int wc   = wid & 1;         // wave col 0..1 (64-col slab)
    const int cl   = lane & 15;       // fragment row/col
    const int rl   = lane >> 4;       // 0..3: k-group

    // Cluster map (bijective): XCD x owns m-tiles [8x, 8x+8); within-XCD order
    // tn-major -> ~96 concurrent blocks/XCD form an 8x12 (MxN) patch:
    // 8 A-slices + 12 B-slices = 320 KB/K-tile, L2-resident.
    const int bid = blockIdx.x;
    const int xcd = bid & 7;
    const int s   = bid >> 3;                 // 0..687
    const int tm  = xcd * 8 + (s & 7);        // 0..63
    const int tn  = s >> 3;                   // 0..85
    const int mBase = tm * BM;
    const int nBase = tn * BN;

    // T2 read-side: element col = (kk*32 + rl*8) ^ ((row&7)<<3); row&7 == cl&7.
    const int colK0 = (rl * 8) ^ ((cl & 7) << 3);
    const int colK1 = colK0 ^ 32;

    f32x4 acc[4][4];   // 64 regs: slab 64x64 = 4x4 fragments
    #pragma unroll
    for (int mi = 0; mi < 4; ++mi)
        #pragma unroll
        for (int ni = 0; ni < 4; ++ni)
            acc[mi][ni] = (f32x4){0.f, 0.f, 0.f, 0.f};

    // Stage one K-tile (A+B), 8 gload_lds(16B)/thread. LDS dest linear (m104);
    // global source col pre-swizzled with the read involution (rule #21).
    #define STAGE_TILE(KCOL_)                                                  \
        { _Pragma("unroll")                                                    \
          for (int it_ = 0; it_ < 4; ++it_) {                                  \
              const int e_ = it_ * 2048 + t * 8;                               \
              const int r_ = e_ >> 6;                                          \
              const int c_ = ((t & 7) * 8) ^ ((r_ & 7) << 3);                  \
              __builtin_amdgcn_global_load_lds(                                \
                  (gmem_void*)(Xb + (size_t)(mBase + r_) * K_DIM + (KCOL_) + c_),\
                  (lds_void*)(lds + e_), 16, 0, 0);                            \
              __builtin_amdgcn_global_load_lds(                                \
                  (gmem_void*)(Wb + (size_t)(nBase + r_) * K_DIM + (KCOL_) + c_),\
                  (lds_void*)(lds + 8192 + e_), 16, 0, 0);                     \
          } }

    STAGE_TILE(0);   // prologue: tile 0 in flight

    for (int kt = 0; kt < NT; ++kt) {
        // barrier 1: drains vmcnt -> tile kt landed & visible block-wide.
        __syncthreads();

        // Fragment reads: 16 ds_read_b128 (A 4x2, B 4x2).
        bf16x8 af[4][2], bf[4][2];
        #pragma unroll
        for (int mi = 0; mi < 4; ++mi) {
            const int row = wr * 64 + mi * 16 + cl;
            af[mi][0] = *(const bf16x8*)(lds + row * 64 + colK0);
            af[mi][1] = *(const bf16x8*)(lds + row * 64 + colK1);
        }
        #pragma unroll
        for (int ni = 0; ni < 4; ++ni) {
            const int row = wc * 64 + ni * 16 + cl;
            bf[ni][0] = *(const bf16x8*)(lds + 8192 + row * 64 + colK0);
            bf[ni][1] = *(const bf16x8*)(lds + 8192 + row * 64 + colK1);
        }

        // barrier 2: waits lgkmcnt(0) -> all reads complete -> safe to
        // overwrite; stage kt+1 NOW so its DMA runs under our MFMAs and
        // other blocks' compute.
        __syncthreads();
        if (kt + 1 < NT) STAGE_TILE((kt + 1) * BK);

        __builtin_amdgcn_s_setprio(1);
        #pragma unroll
        for (int mi = 0; mi < 4; ++mi)
            #pragma unroll
            for (int ni = 0; ni < 4; ++ni) {
                acc[mi][ni] = __builtin_amdgcn_mfma_f32_16x16x32_bf16(
                    af[mi][0], bf[ni][0], acc[mi][ni], 0, 0, 0);
                acc[mi][ni] = __builtin_amdgcn_mfma_f32_16x16x32_bf16(
                    af[mi][1], bf[ni][1], acc[mi][ni], 0, 0, 0);
            }
        __builtin_amdgcn_s_setprio(0);
    }
    #undef STAGE_TILE

    // Epilogue (R8-proven form): out = acc * sx[row] * sw[col] + bias[col].
    // C/D layout: col = lane&15, row = rl*4 + reg (m89/m91). NT stores.
    #pragma unroll
    for (int ni = 0; ni < 4; ++ni) {
        const int col = nBase + wc * 64 + ni * 16 + cl;
        const float swv = SW[col];
        const float bv  = BIAS[col];
        #pragma unroll
        for (int mi = 0; mi < 4; ++mi) {
            const int rowb = mBase + wr * 64 + mi * 16 + rl * 4;
            #pragma unroll
            for (int rr = 0; rr < 4; ++rr) {
                const int row = rowb + rr;
                float v = acc[mi][ni][rr] * SX[row] * swv + bv;
                v = fminf(fmaxf(v, -1.0e5f), 1.0e5f);   // diagnostic sentinel
                __builtin_nontemporal_store(v, OUT + (size_t)row * N_DIM + col);
            }
        }
    }
}

// ---------------- fallback (R7/R8-proven): inline-convert reg-staged 128^2 ----------------
#define FBM 128
#define FBK 64
__global__ __launch_bounds__(256) void linear_flh_gemm_f32in(
    const float* __restrict__ X, const float* __restrict__ SX,
    const float* __restrict__ W, const float* __restrict__ SW,
    const float* __restrict__ BIAS, float* __restrict__ OUT)
{
    __shared__ alignas(16) unsigned short smA[FBM * FBK];
    __shared__ alignas(16) unsigned short smB[FBM * FBK];
    const int t = threadIdx.x;
    const int lane = t & 63, wave = t >> 6;
    const int wr = wave >> 1, wc = wave & 1;
    int bid = blockIdx.x;
    bid = (bid & 7) * ((M_DIM / FBM) * (N_DIM / FBM) / 8) + (bid >> 3);
    const int mBase = (bid / (N_DIM / FBM)) * FBM;
    const int nBase = (bid % (N_DIM / FBM)) * FBM;
    const int cl = lane & 15, rl = lane >> 4;
    f32x4 acc[4][4];
    #pragma unroll
    for (int i = 0; i < 4; ++i)
        #pragma unroll
        for (int j = 0; j < 4; ++j) acc[i][j] = (f32x4){0.f, 0.f, 0.f, 0.f};
    for (int kt = 0; kt < K_DIM / FBK; ++kt) {
        const int kBase = kt * FBK;
        f32x4 ra[8], rb[8];
        #pragma unroll
        for (int cc = 0; cc < 8; ++cc) {
            const int e = cc * 1024 + t * 4;
            const int r = e >> 6, c = e & 63;
            ra[cc] = *(const f32x4*)(X + (size_t)(mBase + r) * K_DIM + kBase + c);
            rb[cc] = *(const f32x4*)(W + (size_t)(nBase + r) * K_DIM + kBase + c);
        }
        __syncthreads();
        #pragma unroll
        for (int cc = 0; cc < 8; ++cc) {
            const int e = cc * 1024 + t * 4;
            u16x4 pa, pb;
            #pragma unroll
            for (int q = 0; q < 4; ++q) { pa[q] = f2bf(ra[cc][q]); pb[q] = f2bf(rb[cc][q]); }
            *(u16x4*)(smA + e) = pa;
            *(u16x4*)(smB + e) = pb;
        }
        __syncthreads();
        #pragma unroll
        for (int kk = 0; kk < FBK / 32; ++kk) {
            bf16x8 afr[4], bfr[4];
            #pragma unroll
            for (int i = 0; i < 4; ++i) {
                afr[i] = *(const bf16x8*)(smA + (wr * 64 + i * 16 + cl) * FBK + kk * 32 + rl * 8);
                bfr[i] = *(const bf16x8*)(smB + (wc * 64 + i * 16 + cl) * FBK + kk * 32 + rl * 8);
            }
            #pragma unroll
            for (int i = 0; i < 4; ++i)
                #pragma unroll
                for (int j = 0; j < 4; ++j)
                    acc[i][j] = __builtin_amdgcn_mfma_f32_16x16x32_bf16(
                        afr[i], bfr[j], acc[i][j], 0, 0, 0);
        }
    }
    #pragma unroll
    for (int j = 0; j < 4; ++j) {
        const int gn = nBase + wc * 64 + j * 16 + cl;
        const float swv = SW[gn], bv = BIAS[gn];
        #pragma unroll
        for (int i = 0; i < 4; ++i) {
            const int gmb = mBase + wr * 64 + i * 16 + rl * 4;
            #pragma unroll
            for (int r = 0; r < 4; ++r) {
                float v = acc[i][j][r] * SX[gmb + r] * swv + bv;
                v = fminf(fmaxf(v, -1.0e5f), 1.0e5f);
                OUT[(size_t)(gmb + r) * N_DIM + gn] = v;
            }
        }
    }
}

extern "C" void kernel_launch(void* const* d_in, const int* in_sizes, int n_in,
                              void* d_out, int out_size, void* d_ws, size_t ws_size,
                              hipStream_t stream) {
    const void* pX = d_in[0]; const void* pSX = d_in[1]; const void* pW = d_in[2];
    const void* pSW = d_in[3]; const void* pBS = d_in[4];
    for (int i = 0; i < n_in; ++i) {
        if (in_sizes[i] == M_DIM * K_DIM)      pX  = d_in[i];
        else if (in_sizes[i] == M_DIM)         pSX = d_in[i];
        else if (in_sizes[i] == N_DIM * K_DIM) pW  = d_in[i];
    }
    {
        int first = -1, second = -1;
        for (int i = 0; i < n_in; ++i)
            if (in_sizes[i] == N_DIM) { if (first < 0) first = i; else if (second < 0) second = i; }
        if (first >= 0)  pSW = d_in[first];
        if (second >= 0) pBS = d_in[second];
    }

    if (ws_size >= WS_NEEDED) {
        unsigned short* Xb = (unsigned short*)d_ws;
        unsigned short* Wb = Xb + X_ELEMS;
        convert_f32_to_bf16<<<2048, 256, 0, stream>>>((const float*)pX, Xb, X_ELEMS);
        convert_f32_to_bf16<<<2048, 256, 0, stream>>>((const float*)pW, Wb, W_ELEMS);
        linear_flh_gemm_128occ<<<dim3(NWG), 256, 0, stream>>>(
            Xb, Wb, (const float*)pSX, (const float*)pSW, (const float*)pBS,
            (float*)d_out);
    } else {
        dim3 grid((M_DIM / FBM) * (N_DIM / FBM));
        linear_flh_gemm_f32in<<<grid, 256, 0, stream>>>(
            (const float*)pX, (const float*)pSX, (const float*)pW,
            (const float*)pSW, (const float*)pBS, (float*)d_out);
    }
}

// Round 20
// 717.584 us; speedup vs baseline: 1.1822x; 1.1822x over previous
//
#include <hip/hip_runtime.h>
#include <hip/hip_bf16.h>

// LinearFLH: out[m,n] = sx[m]*sw[n]*(x[m,:].w[n,:]) + bias[n]
// M=8192, N=11008, K=4096. All harness buffers FLOAT32 (fp16 ref -> "else
// float" rule). Pipeline: (1) single merged f32->bf16 convert of X,W into
// d_ws (NT source loads), (2) R14 CHAMPION GEMM: 256x256/BK=64, 8 waves,
// 4-phase counted-vmcnt (waits 4,4,4,- ; tail 4,2,0), 1 barrier/phase,
// K-synchronized 2D cluster map, T2 XOR swizzle, 16x16x32 MFMA, NT stores.
// Axis tally (R10-R19): schedule x10 (699-793us), traffic (FETCH 1.5->0.55GB),
// instruction (32x32: 4-way conflict, -13%), occupancy/TLP (-21%). R14 is the
// local optimum of this structure space at ~1.06-1.15 PF (42-46% dense peak).

#define M_DIM 8192
#define N_DIM 11008
#define K_DIM 4096
#define BM 256
#define BN 256
#define BK 64
#define NT (K_DIM / BK)                       // 64 K-tiles
#define NWG ((M_DIM / BM) * (N_DIM / BN))     // 32*43 = 1376

#define X_ELEMS (M_DIM * K_DIM)               // 33,554,432 (div by 8)
#define W_ELEMS (N_DIM * K_DIM)               // 45,088,768
#define ALL_ELEMS (X_ELEMS + W_ELEMS)
#define WS_NEEDED ((size_t)ALL_ELEMS * 2)

typedef __bf16 bf16x8 __attribute__((ext_vector_type(8)));
typedef float f32x4 __attribute__((ext_vector_type(4)));
typedef unsigned short u16x4 __attribute__((ext_vector_type(4)));
typedef unsigned short u16x8 __attribute__((ext_vector_type(8)));

typedef __attribute__((address_space(3))) void lds_void;
typedef const __attribute__((address_space(1))) void gmem_void;

// f32 -> bf16 bits, round-to-nearest-even (inputs finite)
__device__ __forceinline__ unsigned short f2bf(float f) {
    union { float f; unsigned int u; } c; c.f = f;
    unsigned int r = c.u + 0x7FFFu + ((c.u >> 16) & 1u);
    return (unsigned short)(r >> 16);
}

// ---------------- merged convert: f32 -> bf16 for X and W in one pass ----------------
// NT loads: the f32 sources are never re-read -> don't pollute L2/L3;
// regular stores keep the bf16 operands (157 MB) L3-resident for the GEMM.
__global__ __launch_bounds__(256) void convert_both_f32_to_bf16(
    const float* __restrict__ X, const float* __restrict__ W,
    unsigned short* __restrict__ Xb, unsigned short* __restrict__ Wb)
{
    int idx = (blockIdx.x * 256 + threadIdx.x) * 8;
    const int stride = gridDim.x * 256 * 8;
    for (; idx < ALL_ELEMS; idx += stride) {
        const float* src;
        unsigned short* dst;
        int off;
        if (idx < X_ELEMS) { src = X; dst = Xb; off = idx; }
        else               { src = W; dst = Wb; off = idx - X_ELEMS; }
        const f32x4 a = __builtin_nontemporal_load((const f32x4*)(src + off));
        const f32x4 b = __builtin_nontemporal_load((const f32x4*)(src + off + 4));
        u16x8 o;
        #pragma unroll
        for (int q = 0; q < 4; ++q) { o[q] = f2bf(a[q]); o[q + 4] = f2bf(b[q]); }
        *(u16x8*)(dst + off) = o;
    }
}

// ---------------- main GEMM: 256x256, 8 waves, 4-phase counted-vmcnt (R14) ----------------
// LDS: buf c at c*32768 (ushort): A [256][64] at +0 (half h at +h*8192),
// B [256][64] at +16384 (half h at +16384+h*8192).
// T2 swizzle (both sides, rule #21): lds[row][col] = global[row][col ^ ((row&7)<<3)].
__global__ __launch_bounds__(512, 2) void linear_flh_gemm_256(
    const unsigned short* __restrict__ Xb,   // [M,K] bf16 bits (ws)
    const unsigned short* __restrict__ Wb,   // [N,K] bf16 bits (ws)
    const float* __restrict__ SX,            // [M]
    const float* __restrict__ SW,            // [N]
    const float* __restrict__ BIAS,          // [N]
    float* __restrict__ OUT)                 // [M,N] f32
{
    __shared__ unsigned short lds[65536];    // 128 KiB -> 1 workgroup/CU

    const int t    = threadIdx.x;     // 0..511
    const int lane = t & 63;
    const int wid  = t >> 6;          // 0..7
    const int qr   = wid >> 2;        // 0..1: wave-row within 128x128 quadrant
    const int wcol = wid & 3;         // 0..3: wave-col within quadrant
    const int cl   = lane & 15;       // fragment row/col
    const int rl   = lane >> 4;       // 0..3: k-group

    // Cluster map (bijective): XCD x owns M-band [4x,4x+4); 32 concurrent
    // CUs = 4x8 MxN patch -> 12 operand slices/K-tile (384 KB) L2-resident.
    const int bid = blockIdx.x;
    const int xcd = bid & 7;
    const int s   = bid >> 3;                 // 0..171
    const int tm  = xcd * 4 + (s & 3);        // 0..31
    const int tn  = s >> 2;                   // 0..42
    const int mBase = tm * BM;
    const int nBase = tn * BN;

    // T2 read-side: element col = (k0) ^ ((row&7)<<3); row&7 == cl&7 below.
    const int colK0 = (rl * 8) ^ ((cl & 7) << 3);
    const int colK1 = colK0 ^ 32;

    f32x4 acc[4][4][2];   // [quadrant mh*2+nh][mi][ni]
    #pragma unroll
    for (int q = 0; q < 4; ++q)
        #pragma unroll
        for (int mi = 0; mi < 4; ++mi)
            #pragma unroll
            for (int ni = 0; ni < 2; ++ni)
                acc[q][mi][ni] = (f32x4){0.f, 0.f, 0.f, 0.f};

    // Stage one 128-row HALF (A or B) = 2 gload_lds(16B)/thread.
    // LDS dest linear (m104); global col pre-swizzled (rule #21).
    #define STAGE_HALF(P_, ROWB_, DSTB_, KCOL_)                                \
        { _Pragma("unroll")                                                    \
          for (int q_ = 0; q_ < 2; ++q_) {                                     \
              const int e_ = q_ * 4096 + t * 8;                                \
              const int r_ = e_ >> 6;                                          \
              const int c_ = ((t & 7) * 8) ^ ((r_ & 7) << 3);                  \
              __builtin_amdgcn_global_load_lds(                                \
                  (gmem_void*)((P_) + (size_t)((ROWB_) + r_) * K_DIM + (KCOL_) + c_),\
                  (lds_void*)(lds + (DSTB_) + e_), 16, 0, 0);                  \
          } }

    #define READ_A(DST_, HB_)                                                  \
        { _Pragma("unroll")                                                    \
          for (int mi_ = 0; mi_ < 4; ++mi_) {                                  \
              const int row_ = qr * 64 + mi_ * 16 + cl;                        \
              DST_[mi_][0] = *(const bf16x8*)(lds + (HB_) + row_ * 64 + colK0);\
              DST_[mi_][1] = *(const bf16x8*)(lds + (HB_) + row_ * 64 + colK1);\
          } }
    #define READ_B(DST_, HB_)                                                  \
        { _Pragma("unroll")                                                    \
          for (int ni_ = 0; ni_ < 2; ++ni_) {                                  \
              const int row_ = wcol * 32 + ni_ * 16 + cl;                      \
              DST_[ni_][0] = *(const bf16x8*)(lds + (HB_) + row_ * 64 + colK0);\
              DST_[ni_][1] = *(const bf16x8*)(lds + (HB_) + row_ * 64 + colK1);\
          } }

    #define MFMA_Q(Q_, AF_, BF_)                                               \
        { __builtin_amdgcn_s_setprio(1);                                       \
          _Pragma("unroll")                                                    \
          for (int mi_ = 0; mi_ < 4; ++mi_)                                    \
              _Pragma("unroll")                                                \
              for (int ni_ = 0; ni_ < 2; ++ni_) {                              \
                  acc[Q_][mi_][ni_] = __builtin_amdgcn_mfma_f32_16x16x32_bf16( \
                      AF_[mi_][0], BF_[ni_][0], acc[Q_][mi_][ni_], 0, 0, 0);   \
                  acc[Q_][mi_][ni_] = __builtin_amdgcn_mfma_f32_16x16x32_bf16( \
                      AF_[mi_][1], BF_[ni_][1], acc[Q_][mi_][ni_], 0, 0, 0);   \
              }                                                                \
          __builtin_amdgcn_s_setprio(0); }

    #define WAITB(VM_)                                                         \
        asm volatile("s_waitcnt vmcnt(" VM_ ")" ::: "memory");                 \
        __builtin_amdgcn_s_barrier();                                          \
        asm volatile("" ::: "memory");

    // Prologue: tile 0 -> buf 0, group order [A0, B0, B1, A1] (8 loads in flight)
    STAGE_HALF(Xb, mBase,        0,             0);
    STAGE_HALF(Wb, nBase,        16384,         0);
    STAGE_HALF(Wb, nBase + 128,  16384 + 8192,  0);
    STAGE_HALF(Xb, mBase + 128,  8192,          0);

    // Main loop (kt < NT-1). Wait derivation (in-order VMEM retirement):
    //  ph0 entry queue [A0,B0,B1,A1]: need A0,B0 -> vmcnt(4); stage A0'.
    //  ph1 entry [B1,A1,A0']<=6: need B1 -> newer {A1,A0'}=4 -> vmcnt(4); stage B0'.
    //  ph2 entry [A1,A0',B0']<=6: need A1 -> newer 4 -> vmcnt(4); stage B1'.
    //  ph3: nothing needed (A1 certified at ph2 barrier) -> no wait/barrier; stage A1'.
    for (int kt = 0; kt < NT - 1; ++kt) {
        const int cur   = kt & 1;
        const int abase = cur * 32768;
        const int bbase = abase + 16384;
        const int ebase = (cur ^ 1) * 32768;
        const int kn    = (kt + 1) * BK;

        bf16x8 a0[4][2], a1[4][2], b0[2][2], b1[2][2];

        // ph0: q00 = A0 x B0
        WAITB("4");
        STAGE_HALF(Xb, mBase, ebase, kn);                       // A0'
        READ_A(a0, abase);
        READ_B(b0, bbase);
        MFMA_Q(0, a0, b0);

        // ph1: q01 = A0 x B1   (A0 carried in registers)
        WAITB("4");
        STAGE_HALF(Wb, nBase, ebase + 16384, kn);               // B0'
        READ_B(b1, bbase + 8192);
        MFMA_Q(1, a0, b1);

        // ph2: q11 = A1 x B1   (B1 carried)
        WAITB("4");
        STAGE_HALF(Wb, nBase + 128, ebase + 16384 + 8192, kn);  // B1'
        READ_A(a1, abase + 8192);
        MFMA_Q(3, a1, b1);

        // ph3: q10 = A1 x B0   (both carried; no wait, no barrier)
        STAGE_HALF(Xb, mBase + 128, ebase + 8192, kn);          // A1'
        MFMA_Q(2, a1, b0);
    }

    // Tail iter kt = NT-1: no staging -> reduced counts (4,2,0).
    {
        const int abase = ((NT - 1) & 1) * 32768;
        const int bbase = abase + 16384;
        bf16x8 a0[4][2], a1[4][2], b0[2][2], b1[2][2];

        WAITB("4");                       // A0,B0 landed
        READ_A(a0, abase);
        READ_B(b0, bbase);
        MFMA_Q(0, a0, b0);

        WAITB("2");                       // B1 landed
        READ_B(b1, bbase + 8192);
        MFMA_Q(1, a0, b1);

        WAITB("0");                       // A1 landed
        READ_A(a1, abase + 8192);
        MFMA_Q(3, a1, b1);

        MFMA_Q(2, a1, b0);
    }

    #undef WAITB
    #undef MFMA_Q
    #undef READ_B
    #undef READ_A
    #undef STAGE_HALF

    // Epilogue: out = acc * sx[row] * sw[col] + bias[col]; NT stores.
    // C/D layout: col = lane&15, row = rl*4 + reg (m89/m91).
    #pragma unroll
    for (int q = 0; q < 4; ++q) {
        const int mh = q >> 1, nh = q & 1;
        #pragma unroll
        for (int mi = 0; mi < 4; ++mi) {
            const int rowb = mBase + mh * 128 + qr * 64 + mi * 16 + rl * 4;
            #pragma unroll
            for (int ni = 0; ni < 2; ++ni) {
                const int col = nBase + nh * 128 + wcol * 32 + ni * 16 + cl;
                const float swv = SW[col];
                const float bv  = BIAS[col];
                #pragma unroll
                for (int rr = 0; rr < 4; ++rr) {
                    const int row = rowb + rr;
                    const float v = acc[q][mi][ni][rr] * SX[row] * swv + bv;
                    __builtin_nontemporal_store(v, OUT + (size_t)row * N_DIM + col);
                }
            }
        }
    }
}

// ---------------- fallback (R7/R8-proven): inline-convert reg-staged 128^2 ----------------
#define FBM 128
#define FBK 64
__global__ __launch_bounds__(256) void linear_flh_gemm_f32in(
    const float* __restrict__ X, const float* __restrict__ SX,
    const float* __restrict__ W, const float* __restrict__ SW,
    const float* __restrict__ BIAS, float* __restrict__ OUT)
{
    __shared__ alignas(16) unsigned short smA[FBM * FBK];
    __shared__ alignas(16) unsigned short smB[FBM * FBK];
    const int t = threadIdx.x;
    const int lane = t & 63, wave = t >> 6;
    const int wr = wave >> 1, wc = wave & 1;
    int bid = blockIdx.x;
    bid = (bid & 7) * ((M_DIM / FBM) * (N_DIM / FBM) / 8) + (bid >> 3);
    const int mBase = (bid / (N_DIM / FBM)) * FBM;
    const int nBase = (bid % (N_DIM / FBM)) * FBM;
    const int cl = lane & 15, rl = lane >> 4;
    f32x4 acc[4][4];
    #pragma unroll
    for (int i = 0; i < 4; ++i)
        #pragma unroll
        for (int j = 0; j < 4; ++j) acc[i][j] = (f32x4){0.f, 0.f, 0.f, 0.f};
    for (int kt = 0; kt < K_DIM / FBK; ++kt) {
        const int kBase = kt * FBK;
        f32x4 ra[8], rb[8];
        #pragma unroll
        for (int cc = 0; cc < 8; ++cc) {
            const int e = cc * 1024 + t * 4;
            const int r = e >> 6, c = e & 63;
            ra[cc] = *(const f32x4*)(X + (size_t)(mBase + r) * K_DIM + kBase + c);
            rb[cc] = *(const f32x4*)(W + (size_t)(nBase + r) * K_DIM + kBase + c);
        }
        __syncthreads();
        #pragma unroll
        for (int cc = 0; cc < 8; ++cc) {
            const int e = cc * 1024 + t * 4;
            u16x4 pa, pb;
            #pragma unroll
            for (int q = 0; q < 4; ++q) { pa[q] = f2bf(ra[cc][q]); pb[q] = f2bf(rb[cc][q]); }
            *(u16x4*)(smA + e) = pa;
            *(u16x4*)(smB + e) = pb;
        }
        __syncthreads();
        #pragma unroll
        for (int kk = 0; kk < FBK / 32; ++kk) {
            bf16x8 afr[4], bfr[4];
            #pragma unroll
            for (int i = 0; i < 4; ++i) {
                afr[i] = *(const bf16x8*)(smA + (wr * 64 + i * 16 + cl) * FBK + kk * 32 + rl * 8);
                bfr[i] = *(const bf16x8*)(smB + (wc * 64 + i * 16 + cl) * FBK + kk * 32 + rl * 8);
            }
            #pragma unroll
            for (int i = 0; i < 4; ++i)
                #pragma unroll
                for (int j = 0; j < 4; ++j)
                    acc[i][j] = __builtin_amdgcn_mfma_f32_16x16x32_bf16(
                        afr[i], bfr[j], acc[i][j], 0, 0, 0);
        }
    }
    #pragma unroll
    for (int j = 0; j < 4; ++j) {
        const int gn = nBase + wc * 64 + j * 16 + cl;
        const float swv = SW[gn], bv = BIAS[gn];
        #pragma unroll
        for (int i = 0; i < 4; ++i) {
            const int gmb = mBase + wr * 64 + i * 16 + rl * 4;
            #pragma unroll
            for (int r = 0; r < 4; ++r)
                OUT[(size_t)(gmb + r) * N_DIM + gn] = acc[i][j][r] * SX[gmb + r] * swv + bv;
        }
    }
}

extern "C" void kernel_launch(void* const* d_in, const int* in_sizes, int n_in,
                              void* d_out, int out_size, void* d_ws, size_t ws_size,
                              hipStream_t stream) {
    const void* pX = d_in[0]; const void* pSX = d_in[1]; const void* pW = d_in[2];
    const void* pSW = d_in[3]; const void* pBS = d_in[4];
    for (int i = 0; i < n_in; ++i) {
        if (in_sizes[i] == M_DIM * K_DIM)      pX  = d_in[i];
        else if (in_sizes[i] == M_DIM)         pSX = d_in[i];
        else if (in_sizes[i] == N_DIM * K_DIM) pW  = d_in[i];
    }
    {
        int first = -1, second = -1;
        for (int i = 0; i < n_in; ++i)
            if (in_sizes[i] == N_DIM) { if (first < 0) first = i; else if (second < 0) second = i; }
        if (first >= 0)  pSW = d_in[first];
        if (second >= 0) pBS = d_in[second];
    }

    if (ws_size >= WS_NEEDED) {
        unsigned short* Xb = (unsigned short*)d_ws;
        unsigned short* Wb = Xb + X_ELEMS;
        convert_both_f32_to_bf16<<<4096, 256, 0, stream>>>(
            (const float*)pX, (const float*)pW, Xb, Wb);
        linear_flh_gemm_256<<<dim3(NWG), 512, 0, stream>>>(
            Xb, Wb, (const float*)pSX, (const float*)pSW, (const float*)pBS,
            (float*)d_out);
    } else {
        dim3 grid((M_DIM / FBM) * (N_DIM / FBM));
        linear_flh_gemm_f32in<<<grid, 256, 0, stream>>>(
            (const float*)pX, (const float*)pSX, (const float*)pW,
            (const float*)pSW, (const float*)pBS, (float*)d_out);
    }
}

// Round 21
// 708.914 us; speedup vs baseline: 1.1967x; 1.0122x over previous
//
#include <hip/hip_runtime.h>
#include <hip/hip_bf16.h>

// LinearFLH: out[m,n] = sx[m]*sw[n]*(x[m,:].w[n,:]) + bias[n]
// M=8192, N=11008, K=4096. All harness buffers FLOAT32 (fp16 ref -> "else
// float" rule). Pipeline: (1) merged f32->bf16 convert of X,W into d_ws,
// (2) 256x256/BK=64 GEMM, 8 waves, K-synchronized 2D cluster map, T2 XOR
// swizzle, 16x16x32 MFMA, counted vmcnt -- R21: phases merged 4 -> 2:
//   ph0: vmcnt(2);barrier; stage A0',B0'; read A0,B0,B1 (16); 32 MFMA q00,q01
//   ph1: vmcnt(4);barrier; stage B1',A1'; read A1 (8);       32 MFMA q11,q10
// (tail: 2,0). One fewer barrier/K-tile; read:MFMA per cluster halves so
// read latency hides under the 32-MFMA cluster. Single variable vs the R20
// champion (696us GEMM, MfmaUtil 48%).

#define M_DIM 8192
#define N_DIM 11008
#define K_DIM 4096
#define BM 256
#define BN 256
#define BK 64
#define NT (K_DIM / BK)                       // 64 K-tiles
#define NWG ((M_DIM / BM) * (N_DIM / BN))     // 32*43 = 1376

#define X_ELEMS (M_DIM * K_DIM)               // 33,554,432
#define W_ELEMS (N_DIM * K_DIM)               // 45,088,768
#define ALL_ELEMS (X_ELEMS + W_ELEMS)
#define WS_NEEDED ((size_t)ALL_ELEMS * 2)

typedef __bf16 bf16x8 __attribute__((ext_vector_type(8)));
typedef float f32x4 __attribute__((ext_vector_type(4)));
typedef unsigned short u16x4 __attribute__((ext_vector_type(4)));
typedef unsigned short u16x8 __attribute__((ext_vector_type(8)));

typedef __attribute__((address_space(3))) void lds_void;
typedef const __attribute__((address_space(1))) void gmem_void;

// f32 -> bf16 bits, round-to-nearest-even (inputs finite)
__device__ __forceinline__ unsigned short f2bf(float f) {
    union { float f; unsigned int u; } c; c.f = f;
    unsigned int r = c.u + 0x7FFFu + ((c.u >> 16) & 1u);
    return (unsigned short)(r >> 16);
}

// ---------------- merged convert: f32 -> bf16 for X and W in one pass ----------------
__global__ __launch_bounds__(256) void convert_both_f32_to_bf16(
    const float* __restrict__ X, const float* __restrict__ W,
    unsigned short* __restrict__ Xb, unsigned short* __restrict__ Wb)
{
    int idx = (blockIdx.x * 256 + threadIdx.x) * 8;
    const int stride = gridDim.x * 256 * 8;
    for (; idx < ALL_ELEMS; idx += stride) {
        const float* src;
        unsigned short* dst;
        int off;
        if (idx < X_ELEMS) { src = X; dst = Xb; off = idx; }
        else               { src = W; dst = Wb; off = idx - X_ELEMS; }
        const f32x4 a = __builtin_nontemporal_load((const f32x4*)(src + off));
        const f32x4 b = __builtin_nontemporal_load((const f32x4*)(src + off + 4));
        u16x8 o;
        #pragma unroll
        for (int q = 0; q < 4; ++q) { o[q] = f2bf(a[q]); o[q + 4] = f2bf(b[q]); }
        *(u16x8*)(dst + off) = o;
    }
}

// ---------------- main GEMM: 256x256, 8 waves, 2-phase counted-vmcnt ----------------
// LDS: buf c at c*32768 (ushort): A [256][64] at +0 (half h at +h*8192),
// B [256][64] at +16384 (half h at +16384+h*8192).
// T2 swizzle (both sides, rule #21): lds[row][col] = global[row][col ^ ((row&7)<<3)].
__global__ __launch_bounds__(512, 2) void linear_flh_gemm_256(
    const unsigned short* __restrict__ Xb,   // [M,K] bf16 bits (ws)
    const unsigned short* __restrict__ Wb,   // [N,K] bf16 bits (ws)
    const float* __restrict__ SX,            // [M]
    const float* __restrict__ SW,            // [N]
    const float* __restrict__ BIAS,          // [N]
    float* __restrict__ OUT)                 // [M,N] f32
{
    __shared__ unsigned short lds[65536];    // 128 KiB -> 1 workgroup/CU

    const int t    = threadIdx.x;     // 0..511
    const int lane = t & 63;
    const int wid  = t >> 6;          // 0..7
    const int qr   = wid >> 2;        // 0..1: wave-row within 128x128 quadrant
    const int wcol = wid & 3;         // 0..3: wave-col within quadrant
    const int cl   = lane & 15;       // fragment row/col
    const int rl   = lane >> 4;       // 0..3: k-group

    // Cluster map (bijective): XCD x owns M-band [4x,4x+4); 32 concurrent
    // CUs = 4x8 MxN patch -> 12 operand slices/K-tile (384 KB) L2-resident.
    const int bid = blockIdx.x;
    const int xcd = bid & 7;
    const int s   = bid >> 3;                 // 0..171
    const int tm  = xcd * 4 + (s & 3);        // 0..31
    const int tn  = s >> 2;                   // 0..42
    const int mBase = tm * BM;
    const int nBase = tn * BN;

    // T2 read-side: element col = (k0) ^ ((row&7)<<3); row&7 == cl&7 below.
    const int colK0 = (rl * 8) ^ ((cl & 7) << 3);
    const int colK1 = colK0 ^ 32;

    f32x4 acc[4][4][2];   // [quadrant mh*2+nh][mi][ni]
    #pragma unroll
    for (int q = 0; q < 4; ++q)
        #pragma unroll
        for (int mi = 0; mi < 4; ++mi)
            #pragma unroll
            for (int ni = 0; ni < 2; ++ni)
                acc[q][mi][ni] = (f32x4){0.f, 0.f, 0.f, 0.f};

    // Stage one 128-row HALF (A or B) = 2 gload_lds(16B)/thread.
    // LDS dest linear (m104); global col pre-swizzled (rule #21).
    #define STAGE_HALF(P_, ROWB_, DSTB_, KCOL_)                                \
        { _Pragma("unroll")                                                    \
          for (int q_ = 0; q_ < 2; ++q_) {                                     \
              const int e_ = q_ * 4096 + t * 8;                                \
              const int r_ = e_ >> 6;                                          \
              const int c_ = ((t & 7) * 8) ^ ((r_ & 7) << 3);                  \
              __builtin_amdgcn_global_load_lds(                                \
                  (gmem_void*)((P_) + (size_t)((ROWB_) + r_) * K_DIM + (KCOL_) + c_),\
                  (lds_void*)(lds + (DSTB_) + e_), 16, 0, 0);                  \
          } }

    #define READ_A(DST_, HB_)                                                  \
        { _Pragma("unroll")                                                    \
          for (int mi_ = 0; mi_ < 4; ++mi_) {                                  \
              const int row_ = qr * 64 + mi_ * 16 + cl;                        \
              DST_[mi_][0] = *(const bf16x8*)(lds + (HB_) + row_ * 64 + colK0);\
              DST_[mi_][1] = *(const bf16x8*)(lds + (HB_) + row_ * 64 + colK1);\
          } }
    #define READ_B(DST_, HB_)                                                  \
        { _Pragma("unroll")                                                    \
          for (int ni_ = 0; ni_ < 2; ++ni_) {                                  \
              const int row_ = wcol * 32 + ni_ * 16 + cl;                      \
              DST_[ni_][0] = *(const bf16x8*)(lds + (HB_) + row_ * 64 + colK0);\
              DST_[ni_][1] = *(const bf16x8*)(lds + (HB_) + row_ * 64 + colK1);\
          } }

    #define MFMA_Q(Q_, AF_, BF_)                                               \
        { __builtin_amdgcn_s_setprio(1);                                       \
          _Pragma("unroll")                                                    \
          for (int mi_ = 0; mi_ < 4; ++mi_)                                    \
              _Pragma("unroll")                                                \
              for (int ni_ = 0; ni_ < 2; ++ni_) {                              \
                  acc[Q_][mi_][ni_] = __builtin_amdgcn_mfma_f32_16x16x32_bf16( \
                      AF_[mi_][0], BF_[ni_][0], acc[Q_][mi_][ni_], 0, 0, 0);   \
                  acc[Q_][mi_][ni_] = __builtin_amdgcn_mfma_f32_16x16x32_bf16( \
                      AF_[mi_][1], BF_[ni_][1], acc[Q_][mi_][ni_], 0, 0, 0);   \
              }                                                                \
          __builtin_amdgcn_s_setprio(0); }

    #define WAITB(VM_)                                                         \
        asm volatile("s_waitcnt vmcnt(" VM_ ")" ::: "memory");                 \
        __builtin_amdgcn_s_barrier();                                          \
        asm volatile("" ::: "memory");

    // Prologue: tile 0 -> buf 0, group order [A0, B0, B1, A1] (8 loads in flight)
    STAGE_HALF(Xb, mBase,        0,             0);
    STAGE_HALF(Wb, nBase,        16384,         0);
    STAGE_HALF(Wb, nBase + 128,  16384 + 8192,  0);
    STAGE_HALF(Xb, mBase + 128,  8192,          0);

    // Main loop (kt < NT-1), 2 phases. Wait derivation (in-order retirement):
    //  ph0 entry queue [A0,B0,B1,A1]: need A0,B0,B1 -> vmcnt(2); stage A0',B0'.
    //  ph1 entry [A1,A0',B0']<=6: need A1 -> newer {A0',B0'}=4 -> vmcnt(4);
    //       stage B1',A1'.
    for (int kt = 0; kt < NT - 1; ++kt) {
        const int cur   = kt & 1;
        const int abase = cur * 32768;
        const int bbase = abase + 16384;
        const int ebase = (cur ^ 1) * 32768;
        const int kn    = (kt + 1) * BK;

        bf16x8 a0[4][2], a1[4][2], b0[2][2], b1[2][2];

        // ph0: q00 + q01  (A0 x B0, A0 x B1)
        WAITB("2");
        STAGE_HALF(Xb, mBase, ebase, kn);                       // A0'
        STAGE_HALF(Wb, nBase, ebase + 16384, kn);               // B0'
        READ_A(a0, abase);
        READ_B(b0, bbase);
        READ_B(b1, bbase + 8192);
        MFMA_Q(0, a0, b0);
        MFMA_Q(1, a0, b1);

        // ph1: q11 + q10  (A1 x B1, A1 x B0)
        WAITB("4");
        STAGE_HALF(Wb, nBase + 128, ebase + 16384 + 8192, kn);  // B1'
        STAGE_HALF(Xb, mBase + 128, ebase + 8192, kn);          // A1'
        READ_A(a1, abase + 8192);
        MFMA_Q(3, a1, b1);
        MFMA_Q(2, a1, b0);
    }

    // Tail iter kt = NT-1: no staging -> reduced counts (2, 0).
    {
        const int abase = ((NT - 1) & 1) * 32768;
        const int bbase = abase + 16384;
        bf16x8 a0[4][2], a1[4][2], b0[2][2], b1[2][2];

        WAITB("2");                       // A0,B0,B1 landed
        READ_A(a0, abase);
        READ_B(b0, bbase);
        READ_B(b1, bbase + 8192);
        MFMA_Q(0, a0, b0);
        MFMA_Q(1, a0, b1);

        WAITB("0");                       // A1 landed
        READ_A(a1, abase + 8192);
        MFMA_Q(3, a1, b1);
        MFMA_Q(2, a1, b0);
    }

    #undef WAITB
    #undef MFMA_Q
    #undef READ_B
    #undef READ_A
    #undef STAGE_HALF

    // Epilogue: out = acc * sx[row] * sw[col] + bias[col]; NT stores.
    // C/D layout: col = lane&15, row = rl*4 + reg (m89/m91).
    #pragma unroll
    for (int q = 0; q < 4; ++q) {
        const int mh = q >> 1, nh = q & 1;
        #pragma unroll
        for (int mi = 0; mi < 4; ++mi) {
            const int rowb = mBase + mh * 128 + qr * 64 + mi * 16 + rl * 4;
            #pragma unroll
            for (int ni = 0; ni < 2; ++ni) {
                const int col = nBase + nh * 128 + wcol * 32 + ni * 16 + cl;
                const float swv = SW[col];
                const float bv  = BIAS[col];
                #pragma unroll
                for (int rr = 0; rr < 4; ++rr) {
                    const int row = rowb + rr;
                    const float v = acc[q][mi][ni][rr] * SX[row] * swv + bv;
                    __builtin_nontemporal_store(v, OUT + (size_t)row * N_DIM + col);
                }
            }
        }
    }
}

// ---------------- fallback (R7/R8-proven): inline-convert reg-staged 128^2 ----------------
#define FBM 128
#define FBK 64
__global__ __launch_bounds__(256) void linear_flh_gemm_f32in(
    const float* __restrict__ X, const float* __restrict__ SX,
    const float* __restrict__ W, const float* __restrict__ SW,
    const float* __restrict__ BIAS, float* __restrict__ OUT)
{
    __shared__ alignas(16) unsigned short smA[FBM * FBK];
    __shared__ alignas(16) unsigned short smB[FBM * FBK];
    const int t = threadIdx.x;
    const int lane = t & 63, wave = t >> 6;
    const int wr = wave >> 1, wc = wave & 1;
    int bid = blockIdx.x;
    bid = (bid & 7) * ((M_DIM / FBM) * (N_DIM / FBM) / 8) + (bid >> 3);
    const int mBase = (bid / (N_DIM / FBM)) * FBM;
    const int nBase = (bid % (N_DIM / FBM)) * FBM;
    const int cl = lane & 15, rl = lane >> 4;
    f32x4 acc[4][4];
    #pragma unroll
    for (int i = 0; i < 4; ++i)
        #pragma unroll
        for (int j = 0; j < 4; ++j) acc[i][j] = (f32x4){0.f, 0.f, 0.f, 0.f};
    for (int kt = 0; kt < K_DIM / FBK; ++kt) {
        const int kBase = kt * FBK;
        f32x4 ra[8], rb[8];
        #pragma unroll
        for (int cc = 0; cc < 8; ++cc) {
            const int e = cc * 1024 + t * 4;
            const int r = e >> 6, c = e & 63;
            ra[cc] = *(const f32x4*)(X + (size_t)(mBase + r) * K_DIM + kBase + c);
            rb[cc] = *(const f32x4*)(W + (size_t)(nBase + r) * K_DIM + kBase + c);
        }
        __syncthreads();
        #pragma unroll
        for (int cc = 0; cc < 8; ++cc) {
            const int e = cc * 1024 + t * 4;
            u16x4 pa, pb;
            #pragma unroll
            for (int q = 0; q < 4; ++q) { pa[q] = f2bf(ra[cc][q]); pb[q] = f2bf(rb[cc][q]); }
            *(u16x4*)(smA + e) = pa;
            *(u16x4*)(smB + e) = pb;
        }
        __syncthreads();
        #pragma unroll
        for (int kk = 0; kk < FBK / 32; ++kk) {
            bf16x8 afr[4], bfr[4];
            #pragma unroll
            for (int i = 0; i < 4; ++i) {
                afr[i] = *(const bf16x8*)(smA + (wr * 64 + i * 16 + cl) * FBK + kk * 32 + rl * 8);
                bfr[i] = *(const bf16x8*)(smB + (wc * 64 + i * 16 + cl) * FBK + kk * 32 + rl * 8);
            }
            #pragma unroll
            for (int i = 0; i < 4; ++i)
                #pragma unroll
                for (int j = 0; j < 4; ++j)
                    acc[i][j] = __builtin_amdgcn_mfma_f32_16x16x32_bf16(
                        afr[i], bfr[j], acc[i][j], 0, 0, 0);
        }
    }
    #pragma unroll
    for (int j = 0; j < 4; ++j) {
        const int gn = nBase + wc * 64 + j * 16 + cl;
        const float swv = SW[gn], bv = BIAS[gn];
        #pragma unroll
        for (int i = 0; i < 4; ++i) {
            const int gmb = mBase + wr * 64 + i * 16 + rl * 4;
            #pragma unroll
            for (int r = 0; r < 4; ++r)
                OUT[(size_t)(gmb + r) * N_DIM + gn] = acc[i][j][r] * SX[gmb + r] * swv + bv;
        }
    }
}

extern "C" void kernel_launch(void* const* d_in, const int* in_sizes, int n_in,
                              void* d_out, int out_size, void* d_ws, size_t ws_size,
                              hipStream_t stream) {
    const void* pX = d_in[0]; const void* pSX = d_in[1]; const void* pW = d_in[2];
    const void* pSW = d_in[3]; const void* pBS = d_in[4];
    for (int i = 0; i < n_in; ++i) {
        if (in_sizes[i] == M_DIM * K_DIM)      pX  = d_in[i];
        else if (in_sizes[i] == M_DIM)         pSX = d_in[i];
        else if (in_sizes[i] == N_DIM * K_DIM) pW  = d_in[i];
    }
    {
        int first = -1, second = -1;
        for (int i = 0; i < n_in; ++i)
            if (in_sizes[i] == N_DIM) { if (first < 0) first = i; else if (second < 0) second = i; }
        if (first >= 0)  pSW = d_in[first];
        if (second >= 0) pBS = d_in[second];
    }

    if (ws_size >= WS_NEEDED) {
        unsigned short* Xb = (unsigned short*)d_ws;
        unsigned short* Wb = Xb + X_ELEMS;
        convert_both_f32_to_bf16<<<4096, 256, 0, stream>>>(
            (const float*)pX, (const float*)pW, Xb, Wb);
        linear_flh_gemm_256<<<dim3(NWG), 512, 0, stream>>>(
            Xb, Wb, (const float*)pSX, (const float*)pSW, (const float*)pBS,
            (float*)d_out);
    } else {
        dim3 grid((M_DIM / FBM) * (N_DIM / FBM));
        linear_flh_gemm_f32in<<<grid, 256, 0, stream>>>(
            (const float*)pX, (const float*)pSX, (const float*)pW,
            (const float*)pSW, (const float*)pBS, (float*)d_out);
    }
}

// Round 22
// 697.343 us; speedup vs baseline: 1.2165x; 1.0166x over previous
//
#include <hip/hip_runtime.h>
#include <hip/hip_bf16.h>

// LinearFLH: out[m,n] = sx[m]*sw[n]*(x[m,:].w[n,:]) + bias[n]
// M=8192, N=11008, K=4096. All harness buffers FLOAT32 (fp16 ref -> "else
// float" rule). FINAL ASSEMBLY of session-best pieces:
//  (1) SEPARATE simple f32->bf16 converts (R8/R14 form; merged-convert cost
//      ~19us: R14 total 698.9 vs R20 717.6 at equal GEMM dispatch time),
//  (2) R14 champion GEMM: 256x256/BK=64, 8 waves, 4-phase counted-vmcnt
//      (waits 4,4,4,-; tail 4,2,0), 1 barrier/phase, K-synchronized 2D
//      cluster map, T2 XOR swizzle, 16x16x32 MFMA, NT stores,
//  (3) clampless epilogue (R20-proven).
// Axis tally (R10-R21): schedule x11 (699-793us, MfmaUtil 42-49%), traffic
// (FETCH 1.5->0.55GB, +5%), instruction shape (32x32: 4-way LDS conflict,
// -13%), occupancy/TLP (-21%). Structural ceiling of this space: ~4850cy/
// K-tile vs 2484cy MFMA floor -> ~1.06 PF (42% dense peak).

#define M_DIM 8192
#define N_DIM 11008
#define K_DIM 4096
#define BM 256
#define BN 256
#define BK 64
#define NT (K_DIM / BK)                       // 64 K-tiles
#define NWG ((M_DIM / BM) * (N_DIM / BN))     // 32*43 = 1376

#define X_ELEMS (M_DIM * K_DIM)               // 33,554,432
#define W_ELEMS (N_DIM * K_DIM)               // 45,088,768
#define WS_NEEDED ((size_t)(X_ELEMS + W_ELEMS) * 2)

typedef __bf16 bf16x8 __attribute__((ext_vector_type(8)));
typedef float f32x4 __attribute__((ext_vector_type(4)));
typedef unsigned short u16x4 __attribute__((ext_vector_type(4)));
typedef unsigned short u16x8 __attribute__((ext_vector_type(8)));

typedef __attribute__((address_space(3))) void lds_void;
typedef const __attribute__((address_space(1))) void gmem_void;

// f32 -> bf16 bits, round-to-nearest-even (inputs finite)
__device__ __forceinline__ unsigned short f2bf(float f) {
    union { float f; unsigned int u; } c; c.f = f;
    unsigned int r = c.u + 0x7FFFu + ((c.u >> 16) & 1u);
    return (unsigned short)(r >> 16);
}

// ---------------- elementwise convert: f32 -> bf16 (R8/R14-proven form) ----------------
__global__ __launch_bounds__(256) void convert_f32_to_bf16(
    const float* __restrict__ in, unsigned short* __restrict__ out, int n)
{
    int idx = (blockIdx.x * 256 + threadIdx.x) * 8;
    const int stride = gridDim.x * 256 * 8;
    for (; idx < n; idx += stride) {
        const f32x4 a = *(const f32x4*)(in + idx);
        const f32x4 b = *(const f32x4*)(in + idx + 4);
        u16x8 o;
        #pragma unroll
        for (int q = 0; q < 4; ++q) { o[q] = f2bf(a[q]); o[q + 4] = f2bf(b[q]); }
        *(u16x8*)(out + idx) = o;
    }
}

// ---------------- main GEMM: 256x256, 8 waves, 4-phase counted-vmcnt (R14) ----------------
// LDS: buf c at c*32768 (ushort): A [256][64] at +0 (half h at +h*8192),
// B [256][64] at +16384 (half h at +16384+h*8192).
// T2 swizzle (both sides, rule #21): lds[row][col] = global[row][col ^ ((row&7)<<3)].
__global__ __launch_bounds__(512, 2) void linear_flh_gemm_256(
    const unsigned short* __restrict__ Xb,   // [M,K] bf16 bits (ws)
    const unsigned short* __restrict__ Wb,   // [N,K] bf16 bits (ws)
    const float* __restrict__ SX,            // [M]
    const float* __restrict__ SW,            // [N]
    const float* __restrict__ BIAS,          // [N]
    float* __restrict__ OUT)                 // [M,N] f32
{
    __shared__ unsigned short lds[65536];    // 128 KiB -> 1 workgroup/CU

    const int t    = threadIdx.x;     // 0..511
    const int lane = t & 63;
    const int wid  = t >> 6;          // 0..7
    const int qr   = wid >> 2;        // 0..1: wave-row within 128x128 quadrant
    const int wcol = wid & 3;         // 0..3: wave-col within quadrant
    const int cl   = lane & 15;       // fragment row/col
    const int rl   = lane >> 4;       // 0..3: k-group

    // Cluster map (bijective): XCD x owns M-band [4x,4x+4); 32 concurrent
    // CUs = 4x8 MxN patch -> 12 operand slices/K-tile (384 KB) L2-resident.
    const int bid = blockIdx.x;
    const int xcd = bid & 7;
    const int s   = bid >> 3;                 // 0..171
    const int tm  = xcd * 4 + (s & 3);        // 0..31
    const int tn  = s >> 2;                   // 0..42
    const int mBase = tm * BM;
    const int nBase = tn * BN;

    // T2 read-side: element col = (k0) ^ ((row&7)<<3); row&7 == cl&7 below.
    const int colK0 = (rl * 8) ^ ((cl & 7) << 3);
    const int colK1 = colK0 ^ 32;

    f32x4 acc[4][4][2];   // [quadrant mh*2+nh][mi][ni]
    #pragma unroll
    for (int q = 0; q < 4; ++q)
        #pragma unroll
        for (int mi = 0; mi < 4; ++mi)
            #pragma unroll
            for (int ni = 0; ni < 2; ++ni)
                acc[q][mi][ni] = (f32x4){0.f, 0.f, 0.f, 0.f};

    // Stage one 128-row HALF (A or B) = 2 gload_lds(16B)/thread.
    // LDS dest linear (m104); global col pre-swizzled (rule #21).
    #define STAGE_HALF(P_, ROWB_, DSTB_, KCOL_)                                \
        { _Pragma("unroll")                                                    \
          for (int q_ = 0; q_ < 2; ++q_) {                                     \
              const int e_ = q_ * 4096 + t * 8;                                \
              const int r_ = e_ >> 6;                                          \
              const int c_ = ((t & 7) * 8) ^ ((r_ & 7) << 3);                  \
              __builtin_amdgcn_global_load_lds(                                \
                  (gmem_void*)((P_) + (size_t)((ROWB_) + r_) * K_DIM + (KCOL_) + c_),\
                  (lds_void*)(lds + (DSTB_) + e_), 16, 0, 0);                  \
          } }

    #define READ_A(DST_, HB_)                                                  \
        { _Pragma("unroll")                                                    \
          for (int mi_ = 0; mi_ < 4; ++mi_) {                                  \
              const int row_ = qr * 64 + mi_ * 16 + cl;                        \
              DST_[mi_][0] = *(const bf16x8*)(lds + (HB_) + row_ * 64 + colK0);\
              DST_[mi_][1] = *(const bf16x8*)(lds + (HB_) + row_ * 64 + colK1);\
          } }
    #define READ_B(DST_, HB_)                                                  \
        { _Pragma("unroll")                                                    \
          for (int ni_ = 0; ni_ < 2; ++ni_) {                                  \
              const int row_ = wcol * 32 + ni_ * 16 + cl;                      \
              DST_[ni_][0] = *(const bf16x8*)(lds + (HB_) + row_ * 64 + colK0);\
              DST_[ni_][1] = *(const bf16x8*)(lds + (HB_) + row_ * 64 + colK1);\
          } }

    #define MFMA_Q(Q_, AF_, BF_)                                               \
        { __builtin_amdgcn_s_setprio(1);                                       \
          _Pragma("unroll")                                                    \
          for (int mi_ = 0; mi_ < 4; ++mi_)                                    \
              _Pragma("unroll")                                                \
              for (int ni_ = 0; ni_ < 2; ++ni_) {                              \
                  acc[Q_][mi_][ni_] = __builtin_amdgcn_mfma_f32_16x16x32_bf16( \
                      AF_[mi_][0], BF_[ni_][0], acc[Q_][mi_][ni_], 0, 0, 0);   \
                  acc[Q_][mi_][ni_] = __builtin_amdgcn_mfma_f32_16x16x32_bf16( \
                      AF_[mi_][1], BF_[ni_][1], acc[Q_][mi_][ni_], 0, 0, 0);   \
              }                                                                \
          __builtin_amdgcn_s_setprio(0); }

    #define WAITB(VM_)                                                         \
        asm volatile("s_waitcnt vmcnt(" VM_ ")" ::: "memory");                 \
        __builtin_amdgcn_s_barrier();                                          \
        asm volatile("" ::: "memory");

    // Prologue: tile 0 -> buf 0, group order [A0, B0, B1, A1] (8 loads in flight)
    STAGE_HALF(Xb, mBase,        0,             0);
    STAGE_HALF(Wb, nBase,        16384,         0);
    STAGE_HALF(Wb, nBase + 128,  16384 + 8192,  0);
    STAGE_HALF(Xb, mBase + 128,  8192,          0);

    // Main loop (kt < NT-1). Wait derivation (in-order VMEM retirement):
    //  ph0 entry queue [A0,B0,B1,A1]: need A0,B0 -> vmcnt(4); stage A0'.
    //  ph1 entry [B1,A1,A0']<=6: need B1 -> newer {A1,A0'}=4 -> vmcnt(4); stage B0'.
    //  ph2 entry [A1,A0',B0']<=6: need A1 -> newer 4 -> vmcnt(4); stage B1'.
    //  ph3: nothing needed (A1 certified at ph2 barrier) -> no wait/barrier; stage A1'.
    for (int kt = 0; kt < NT - 1; ++kt) {
        const int cur   = kt & 1;
        const int abase = cur * 32768;
        const int bbase = abase + 16384;
        const int ebase = (cur ^ 1) * 32768;
        const int kn    = (kt + 1) * BK;

        bf16x8 a0[4][2], a1[4][2], b0[2][2], b1[2][2];

        // ph0: q00 = A0 x B0
        WAITB("4");
        STAGE_HALF(Xb, mBase, ebase, kn);                       // A0'
        READ_A(a0, abase);
        READ_B(b0, bbase);
        MFMA_Q(0, a0, b0);

        // ph1: q01 = A0 x B1   (A0 carried in registers)
        WAITB("4");
        STAGE_HALF(Wb, nBase, ebase + 16384, kn);               // B0'
        READ_B(b1, bbase + 8192);
        MFMA_Q(1, a0, b1);

        // ph2: q11 = A1 x B1   (B1 carried)
        WAITB("4");
        STAGE_HALF(Wb, nBase + 128, ebase + 16384 + 8192, kn);  // B1'
        READ_A(a1, abase + 8192);
        MFMA_Q(3, a1, b1);

        // ph3: q10 = A1 x B0   (both carried; no wait, no barrier)
        STAGE_HALF(Xb, mBase + 128, ebase + 8192, kn);          // A1'
        MFMA_Q(2, a1, b0);
    }

    // Tail iter kt = NT-1: no staging -> reduced counts (4,2,0).
    {
        const int abase = ((NT - 1) & 1) * 32768;
        const int bbase = abase + 16384;
        bf16x8 a0[4][2], a1[4][2], b0[2][2], b1[2][2];

        WAITB("4");                       // A0,B0 landed
        READ_A(a0, abase);
        READ_B(b0, bbase);
        MFMA_Q(0, a0, b0);

        WAITB("2");                       // B1 landed
        READ_B(b1, bbase + 8192);
        MFMA_Q(1, a0, b1);

        WAITB("0");                       // A1 landed
        READ_A(a1, abase + 8192);
        MFMA_Q(3, a1, b1);

        MFMA_Q(2, a1, b0);
    }

    #undef WAITB
    #undef MFMA_Q
    #undef READ_B
    #undef READ_A
    #undef STAGE_HALF

    // Epilogue: out = acc * sx[row] * sw[col] + bias[col]; NT stores.
    // C/D layout: col = lane&15, row = rl*4 + reg (m89/m91).
    #pragma unroll
    for (int q = 0; q < 4; ++q) {
        const int mh = q >> 1, nh = q & 1;
        #pragma unroll
        for (int mi = 0; mi < 4; ++mi) {
            const int rowb = mBase + mh * 128 + qr * 64 + mi * 16 + rl * 4;
            #pragma unroll
            for (int ni = 0; ni < 2; ++ni) {
                const int col = nBase + nh * 128 + wcol * 32 + ni * 16 + cl;
                const float swv = SW[col];
                const float bv  = BIAS[col];
                #pragma unroll
                for (int rr = 0; rr < 4; ++rr) {
                    const int row = rowb + rr;
                    const float v = acc[q][mi][ni][rr] * SX[row] * swv + bv;
                    __builtin_nontemporal_store(v, OUT + (size_t)row * N_DIM + col);
                }
            }
        }
    }
}

// ---------------- fallback (R7/R8-proven): inline-convert reg-staged 128^2 ----------------
#define FBM 128
#define FBK 64
__global__ __launch_bounds__(256) void linear_flh_gemm_f32in(
    const float* __restrict__ X, const float* __restrict__ SX,
    const float* __restrict__ W, const float* __restrict__ SW,
    const float* __restrict__ BIAS, float* __restrict__ OUT)
{
    __shared__ alignas(16) unsigned short smA[FBM * FBK];
    __shared__ alignas(16) unsigned short smB[FBM * FBK];
    const int t = threadIdx.x;
    const int lane = t & 63, wave = t >> 6;
    const int wr = wave >> 1, wc = wave & 1;
    int bid = blockIdx.x;
    bid = (bid & 7) * ((M_DIM / FBM) * (N_DIM / FBM) / 8) + (bid >> 3);
    const int mBase = (bid / (N_DIM / FBM)) * FBM;
    const int nBase = (bid % (N_DIM / FBM)) * FBM;
    const int cl = lane & 15, rl = lane >> 4;
    f32x4 acc[4][4];
    #pragma unroll
    for (int i = 0; i < 4; ++i)
        #pragma unroll
        for (int j = 0; j < 4; ++j) acc[i][j] = (f32x4){0.f, 0.f, 0.f, 0.f};
    for (int kt = 0; kt < K_DIM / FBK; ++kt) {
        const int kBase = kt * FBK;
        f32x4 ra[8], rb[8];
        #pragma unroll
        for (int cc = 0; cc < 8; ++cc) {
            const int e = cc * 1024 + t * 4;
            const int r = e >> 6, c = e & 63;
            ra[cc] = *(const f32x4*)(X + (size_t)(mBase + r) * K_DIM + kBase + c);
            rb[cc] = *(const f32x4*)(W + (size_t)(nBase + r) * K_DIM + kBase + c);
        }
        __syncthreads();
        #pragma unroll
        for (int cc = 0; cc < 8; ++cc) {
            const int e = cc * 1024 + t * 4;
            u16x4 pa, pb;
            #pragma unroll
            for (int q = 0; q < 4; ++q) { pa[q] = f2bf(ra[cc][q]); pb[q] = f2bf(rb[cc][q]); }
            *(u16x4*)(smA + e) = pa;
            *(u16x4*)(smB + e) = pb;
        }
        __syncthreads();
        #pragma unroll
        for (int kk = 0; kk < FBK / 32; ++kk) {
            bf16x8 afr[4], bfr[4];
            #pragma unroll
            for (int i = 0; i < 4; ++i) {
                afr[i] = *(const bf16x8*)(smA + (wr * 64 + i * 16 + cl) * FBK + kk * 32 + rl * 8);
                bfr[i] = *(const bf16x8*)(smB + (wc * 64 + i * 16 + cl) * FBK + kk * 32 + rl * 8);
            }
            #pragma unroll
            for (int i = 0; i < 4; ++i)
                #pragma unroll
                for (int j = 0; j < 4; ++j)
                    acc[i][j] = __builtin_amdgcn_mfma_f32_16x16x32_bf16(
                        afr[i], bfr[j], acc[i][j], 0, 0, 0);
        }
    }
    #pragma unroll
    for (int j = 0; j < 4; ++j) {
        const int gn = nBase + wc * 64 + j * 16 + cl;
        const float swv = SW[gn], bv = BIAS[gn];
        #pragma unroll
        for (int i = 0; i < 4; ++i) {
            const int gmb = mBase + wr * 64 + i * 16 + rl * 4;
            #pragma unroll
            for (int r = 0; r < 4; ++r)
                OUT[(size_t)(gmb + r) * N_DIM + gn] = acc[i][j][r] * SX[gmb + r] * swv + bv;
        }
    }
}

extern "C" void kernel_launch(void* const* d_in, const int* in_sizes, int n_in,
                              void* d_out, int out_size, void* d_ws, size_t ws_size,
                              hipStream_t stream) {
    const void* pX = d_in[0]; const void* pSX = d_in[1]; const void* pW = d_in[2];
    const void* pSW = d_in[3]; const void* pBS = d_in[4];
    for (int i = 0; i < n_in; ++i) {
        if (in_sizes[i] == M_DIM * K_DIM)      pX  = d_in[i];
        else if (in_sizes[i] == M_DIM)         pSX = d_in[i];
        else if (in_sizes[i] == N_DIM * K_DIM) pW  = d_in[i];
    }
    {
        int first = -1, second = -1;
        for (int i = 0; i < n_in; ++i)
            if (in_sizes[i] == N_DIM) { if (first < 0) first = i; else if (second < 0) second = i; }
        if (first >= 0)  pSW = d_in[first];
        if (second >= 0) pBS = d_in[second];
    }

    if (ws_size >= WS_NEEDED) {
        unsigned short* Xb = (unsigned short*)d_ws;
        unsigned short* Wb = Xb + X_ELEMS;
        convert_f32_to_bf16<<<2048, 256, 0, stream>>>((const float*)pX, Xb, X_ELEMS);
        convert_f32_to_bf16<<<2048, 256, 0, stream>>>((const float*)pW, Wb, W_ELEMS);
        linear_flh_gemm_256<<<dim3(NWG), 512, 0, stream>>>(
            Xb, Wb, (const float*)pSX, (const float*)pSW, (const float*)pBS,
            (float*)d_out);
    } else {
        dim3 grid((M_DIM / FBM) * (N_DIM / FBM));
        linear_flh_gemm_f32in<<<grid, 256, 0, stream>>>(
            (const float*)pX, (const float*)pSX, (const float*)pW,
            (const float*)pSW, (const float*)pBS, (float*)d_out);
    }
}